// Round 2
// baseline (346.488 us; speedup 1.0000x reference)
//
#include <hip/hip_runtime.h>
#include <stdint.h>

typedef __attribute__((ext_vector_type(8))) short short8;
typedef __attribute__((ext_vector_type(4))) float f32x4;

#define S_LEN 2048
#define HID 2048
#define NH 16
#define NKV 4
#define DH 128
#define WINDOW 1024
#define SCALE 0.08838834764831845f

__device__ __forceinline__ unsigned short f2bf(float f) {
    unsigned int u = __float_as_uint(f);
    unsigned int r = (u + 0x7fffu + ((u >> 16) & 1u)) >> 16;
    return (unsigned short)r;
}

__device__ __forceinline__ float bf2f(unsigned short u) {
    return __uint_as_float((unsigned int)u << 16);
}

__device__ __forceinline__ void gload16(const void* g, void* l) {
    __builtin_amdgcn_global_load_lds((__attribute__((address_space(1))) void*)g,
                                     (__attribute__((address_space(3))) void*)l, 16, 0, 0);
}

// ---------------- prep kernels ----------------

__global__ __launch_bounds__(256) void cast4_kernel(const float* __restrict__ src,
                                                    unsigned short* __restrict__ dst, int n4) {
    int i = blockIdx.x * 256 + threadIdx.x;
    if (i < n4) {
        float4 v = ((const float4*)src)[i];
        ushort4 o;
        o.x = f2bf(v.x); o.y = f2bf(v.y); o.z = f2bf(v.z); o.w = f2bf(v.w);
        ((ushort4*)dst)[i] = o;
    }
}

__global__ __launch_bounds__(256) void build_bias_kernel(const float* __restrict__ bq,
                                                         const float* __restrict__ bk,
                                                         const float* __restrict__ bv,
                                                         float* __restrict__ cbias) {
    int i = blockIdx.x * 256 + threadIdx.x;
    if (i < 3072) {
        float v;
        if (i < 2048) v = bq[i];
        else if (i < 2560) v = bk[i - 2048];
        else v = bv[i - 2560];
        cbias[i] = v;
    }
}

// src: K x N (f32), dst: (N x K) bf16 at row offset rowoff, row stride K
__global__ __launch_bounds__(256) void transpose_cast_kernel(const float* __restrict__ src,
                                                             unsigned short* __restrict__ dst,
                                                             int N, int K, int rowoff) {
    __shared__ unsigned short t[32][33];
    int n0 = blockIdx.x * 32, k0 = blockIdx.y * 32;
    int c = threadIdx.x & 31, r8 = threadIdx.x >> 5;
#pragma unroll
    for (int i = 0; i < 4; i++) {
        int r = r8 + i * 8;
        t[r][c] = f2bf(src[(size_t)(k0 + r) * N + n0 + c]);
    }
    __syncthreads();
#pragma unroll
    for (int i = 0; i < 4; i++) {
        int r = r8 + i * 8;
        dst[(size_t)(rowoff + n0 + r) * K + k0 + c] = t[c][r];
    }
}

// ---------------- GEMM: C[M,N] = A[M,K] * Bt[N,K]^T (+bias) ----------------
// 128x64 tile, BK=32, double-buffered global_load_lds staging.

template <bool BF16OUT>
__global__ __launch_bounds__(256) void gemm_bf16(const unsigned short* __restrict__ A,
                                                 const unsigned short* __restrict__ Bt,
                                                 void* __restrict__ Cv,
                                                 const float* __restrict__ bias,
                                                 int M, int N, int K) {
    __shared__ unsigned short Al[2][128 * 32];
    __shared__ unsigned short Bl[2][64 * 32];
    const int tid = threadIdx.x;
    const int lane = tid & 63;
    const int w = tid >> 6;
    const int nbn = N >> 6;
    const int bm = blockIdx.x / nbn, bn = blockIdx.x % nbn;
    const int m0 = bm << 7, n0 = bn << 6;
    const int wr = w >> 1, wc = w & 1;

    const int lin0 = tid * 16;
    const int r0 = lin0 >> 6, b0 = lin0 & 63;
    const int lin1 = 4096 + tid * 16;
    const int r1 = lin1 >> 6, b1 = lin1 & 63;
    const size_t Kb = (size_t)K * 2;

    const char* Ab = (const char*)A + (size_t)m0 * Kb;
    const char* Bb = (const char*)Bt + (size_t)n0 * Kb;
    char* Al0 = (char*)&Al[0][0];
    char* Bl0 = (char*)&Bl[0][0];
    const int wb = w * 1024;

    auto stage = [&](int buf, int kt) {
        const char* Ak = Ab + kt * 64;
        const char* Bk = Bb + kt * 64;
        char* Ad = Al0 + buf * 8192;
        char* Bd = Bl0 + buf * 4096;
        gload16(Ak + (size_t)r0 * Kb + b0, Ad + wb);
        gload16(Ak + (size_t)r1 * Kb + b1, Ad + 4096 + wb);
        gload16(Bk + (size_t)r0 * Kb + b0, Bd + wb);
    };

    f32x4 acc[4][2] = {};
    const int NT = K >> 5;
    stage(0, 0);
    for (int kt = 0; kt < NT; ++kt) {
        __syncthreads();
        if (kt + 1 < NT) stage((kt + 1) & 1, kt + 1);
        const char* Ar = (const char*)&Al[kt & 1][0];
        const char* Br = (const char*)&Bl[kt & 1][0];
        const int ko = (lane >> 4) * 16;
        short8 af[4], bfr[2];
#pragma unroll
        for (int m = 0; m < 4; m++)
            af[m] = *(const short8*)(Ar + (wr * 64 + m * 16 + (lane & 15)) * 64 + ko);
#pragma unroll
        for (int n = 0; n < 2; n++)
            bfr[n] = *(const short8*)(Br + (wc * 32 + n * 16 + (lane & 15)) * 64 + ko);
#pragma unroll
        for (int m = 0; m < 4; m++)
#pragma unroll
            for (int n = 0; n < 2; n++)
                acc[m][n] = __builtin_amdgcn_mfma_f32_16x16x32_bf16(af[m], bfr[n], acc[m][n], 0, 0, 0);
        __syncthreads();
    }

#pragma unroll
    for (int m = 0; m < 4; m++) {
        const int row = m0 + wr * 64 + m * 16 + (lane >> 4) * 4;
#pragma unroll
        for (int n = 0; n < 2; n++) {
            const int col = n0 + wc * 32 + n * 16 + (lane & 15);
            const float badd = bias ? bias[col] : 0.f;
#pragma unroll
            for (int r = 0; r < 4; r++) {
                const float v = acc[m][n][r] + badd;
                if constexpr (BF16OUT)
                    ((unsigned short*)Cv)[(size_t)(row + r) * N + col] = f2bf(v);
                else
                    ((float*)Cv)[(size_t)(row + r) * N + col] = v;
            }
        }
    }
}

// ---------------- RoPE + layout ----------------
// qkv: [S][3072] bf16  ->  Qr [16][S][128], Kr [4][S][128], Vt [4][128][S] (bf16)
__global__ __launch_bounds__(256) void rope_kernel(const unsigned short* __restrict__ qkv,
                                                   unsigned short* __restrict__ Qr,
                                                   unsigned short* __restrict__ Kr,
                                                   unsigned short* __restrict__ Vt) {
    int s = blockIdx.x, tid = threadIdx.x;
    __shared__ float cs[64], sn[64];
    if (tid < 64) {
        float inv = __expf(-(float)tid * (logf(10000.f) / 64.f));
        float ang = (float)s * inv;
        float si, co;
        sincosf(ang, &si, &co);
        cs[tid] = co;
        sn[tid] = si;
    }
    __syncthreads();
    const unsigned short* row = qkv + (size_t)s * 3072;
#pragma unroll
    for (int it = 0; it < 8; ++it) {
        int j = tid + it * 256;
        int h = j >> 7, d = j & 127, f = d & 63;
        float x = bf2f(row[j]);
        float other = bf2f(row[(j & ~127) + (d ^ 64)]);
        float v = (d < 64) ? x * cs[f] - other * sn[f] : x * cs[f] + other * sn[f];
        Qr[((size_t)h * S_LEN + s) * 128 + d] = f2bf(v);
    }
#pragma unroll
    for (int it = 0; it < 2; ++it) {
        int j = tid + it * 256;
        int kvh = j >> 7, d = j & 127, f = d & 63;
        float x = bf2f(row[2048 + j]);
        float other = bf2f(row[2048 + (j & ~127) + (d ^ 64)]);
        float v = (d < 64) ? x * cs[f] - other * sn[f] : x * cs[f] + other * sn[f];
        Kr[((size_t)kvh * S_LEN + s) * 128 + d] = f2bf(v);
        Vt[((size_t)kvh * 128 + d) * S_LEN + s] = row[2560 + j];
    }
}

// ---------------- flash attention, sliding window, GQA ----------------
// K/V fragments read directly from global (L2-resident: 512 KB per kv-head).
// Only P goes through LDS (per-wave buffer) -> zero __syncthreads.

__global__ __launch_bounds__(256) void attn_kernel(const unsigned short* __restrict__ Qr,
                                                   const unsigned short* __restrict__ Kr,
                                                   const unsigned short* __restrict__ Vt,
                                                   const float* __restrict__ mg,
                                                   unsigned short* __restrict__ Ao) {
    __shared__ unsigned short Pl[4][16 * 64];  // per-wave, swizzled rows of 128B
    const int tid = threadIdx.x, lane = tid & 63, w = tid >> 6;
    const int h = blockIdx.y, qt = blockIdx.x;
    const int kvh = h >> 2;
    const int q0 = qt * 64;
    const int lo = lane & 15, hi = lane >> 4;

    const unsigned short* Qb =
        Qr + ((size_t)h * S_LEN + q0 + w * 16 + lo) * 128 + hi * 8;
    short8 qf[4];
#pragma unroll
    for (int ks = 0; ks < 4; ++ks) qf[ks] = *(const short8*)(Qb + ks * 32);

    const float gate = 1.f / (1.f + __expf(-mg[h]));
    const float fac = 1.f - gate;

    float mrow[4] = {-INFINITY, -INFINITY, -INFINITY, -INFINITY};
    float lrow[4] = {0.f, 0.f, 0.f, 0.f};
    f32x4 o[8] = {};

    const char* Kg = (const char*)(Kr + (size_t)kvh * S_LEN * 128);
    const char* Vg = (const char*)(Vt + (size_t)kvh * 128 * S_LEN);
    char* Pw = (char*)&Pl[w][0];

    const int t0 = (q0 >= 1023) ? (q0 - 1023) >> 6 : 0;
    for (int kt = t0; kt <= qt; ++kt) {
        const int k0 = kt * 64;

        // QK^T : per wave 16 q-rows x 64 k-cols, K from global (L2)
        f32x4 sc[4];
#pragma unroll
        for (int t = 0; t < 4; t++) {
            sc[t] = (f32x4){0.f, 0.f, 0.f, 0.f};
            const size_t krow = (size_t)(k0 + t * 16 + lo);
#pragma unroll
            for (int ks = 0; ks < 4; ks++) {
                short8 kf = *(const short8*)(Kg + krow * 256 + (ks * 4 + hi) * 16);
                sc[t] = __builtin_amdgcn_mfma_f32_16x16x32_bf16(qf[ks], kf, sc[t], 0, 0, 0);
            }
        }

        // online softmax (rows split 4-per-lane-group, 16-lane shuffle reduce)
        const int qrow_base = q0 + w * 16 + hi * 4;
        float alpha[4];
        float ps[4][4];
#pragma unroll
        for (int r = 0; r < 4; r++) {
            const int q = qrow_base + r;
            float mt = -INFINITY;
#pragma unroll
            for (int t = 0; t < 4; t++) {
                const int k = k0 + t * 16 + lo;
                const bool valid = (k <= q) && (q - k < WINDOW);
                float sv = valid ? sc[t][r] * SCALE : -INFINITY;
                ps[t][r] = sv;
                mt = fmaxf(mt, sv);
            }
#pragma unroll
            for (int off = 1; off < 16; off <<= 1) mt = fmaxf(mt, __shfl_xor(mt, off, 64));
            float mn = fmaxf(mrow[r], mt);
            alpha[r] = (mn == -INFINITY) ? 1.f : __expf(mrow[r] - mn);
            float ls = 0.f;
#pragma unroll
            for (int t = 0; t < 4; t++) {
                float p = (ps[t][r] == -INFINITY) ? 0.f : __expf(ps[t][r] - mn);
                ps[t][r] = p;
                ls += p;
            }
#pragma unroll
            for (int off = 1; off < 16; off <<= 1) ls += __shfl_xor(ls, off, 64);
            lrow[r] = lrow[r] * alpha[r] + ls;
            mrow[r] = mn;
        }

        // P -> LDS (bf16, swizzled 128B rows)
#pragma unroll
        for (int r = 0; r < 4; r++) {
            const int prow = hi * 4 + r;
#pragma unroll
            for (int t = 0; t < 4; t++) {
                const int col = t * 16 + lo;
                const int chunk = col >> 3;
                *(unsigned short*)(Pw + prow * 128 + ((chunk ^ (prow & 7)) << 4) + (col & 7) * 2) =
                    f2bf(ps[t][r]);
            }
        }
        asm volatile("s_waitcnt lgkmcnt(0)" ::: "memory");
        __builtin_amdgcn_sched_barrier(0);

        // rescale O
#pragma unroll
        for (int n = 0; n < 8; n++)
#pragma unroll
            for (int r = 0; r < 4; r++) o[n][r] *= alpha[r];

        // PV: V^T fragments from global (L2), P from per-wave LDS
#pragma unroll
        for (int n = 0; n < 8; n++) {
            const int d = n * 16 + lo;
#pragma unroll
            for (int ks = 0; ks < 2; ++ks) {
                const int chunk = ks * 4 + hi;
                const int prow = lo;
                short8 pa = *(const short8*)(Pw + prow * 128 + ((chunk ^ (prow & 7)) << 4));
                short8 vbf = *(const short8*)(Vg + (size_t)d * (S_LEN * 2) +
                                              (size_t)(k0 + ks * 32 + hi * 8) * 2);
                o[n] = __builtin_amdgcn_mfma_f32_16x16x32_bf16(pa, vbf, o[n], 0, 0, 0);
            }
        }
    }

    // epilogue: out = (1-gate) * local / l
#pragma unroll
    for (int r = 0; r < 4; r++) {
        const int s = q0 + w * 16 + hi * 4 + r;
        const float inv = fac / lrow[r];
#pragma unroll
        for (int n = 0; n < 8; n++) {
            const int d = n * 16 + lo;
            Ao[(size_t)s * 2048 + h * 128 + d] = f2bf(o[n][r] * inv);
        }
    }
}

// ---------------- launch ----------------

extern "C" void kernel_launch(void* const* d_in, const int* in_sizes, int n_in,
                              void* d_out, int out_size, void* d_ws, size_t ws_size,
                              hipStream_t stream) {
    const float* hs = (const float*)d_in[0];
    const float* Wq = (const float*)d_in[1];
    const float* bq = (const float*)d_in[2];
    const float* Wk = (const float*)d_in[3];
    const float* bk = (const float*)d_in[4];
    const float* Wv = (const float*)d_in[5];
    const float* bv = (const float*)d_in[6];
    const float* Wo = (const float*)d_in[7];
    const float* mg = (const float*)d_in[8];

    char* ws = (char*)d_ws;
    // region layout (bytes)
    unsigned short* hsb   = (unsigned short*)(ws + 0);          // 8 MB, dead after QKV gemm
    unsigned short* woT   = (unsigned short*)(ws + 0);          // reuses hsb region (8 MB)
    unsigned short* wqkvT = (unsigned short*)(ws + 8388608);    // 12 MB, dead after QKV gemm
    unsigned short* attnb = (unsigned short*)(ws + 8388608);    // reuses wqkvT region (8 MB)
    unsigned short* qkvb  = (unsigned short*)(ws + 20971520);   // 12 MB, dead after rope
    unsigned short* Qrb   = (unsigned short*)(ws + 33554432);   // 8 MB
    unsigned short* Krb   = (unsigned short*)(ws + 41943040);   // 2 MB
    unsigned short* Vtb   = (unsigned short*)(ws + 44040192);   // 2 MB
    float*          cbias = (float*)(ws + 46137344);            // 12 KB

    // prep
    cast4_kernel<<<4096, 256, 0, stream>>>(hs, hsb, 1048576);
    build_bias_kernel<<<12, 256, 0, stream>>>(bq, bk, bv, cbias);
    transpose_cast_kernel<<<dim3(64, 64), 256, 0, stream>>>(Wq, wqkvT, 2048, 2048, 0);
    transpose_cast_kernel<<<dim3(16, 64), 256, 0, stream>>>(Wk, wqkvT, 512, 2048, 2048);
    transpose_cast_kernel<<<dim3(16, 64), 256, 0, stream>>>(Wv, wqkvT, 512, 2048, 2560);

    // QKV projection: [2048,2048] x [2048,3072] (+bias), bf16 out
    gemm_bf16<true><<<16 * 48, 256, 0, stream>>>(hsb, wqkvT, qkvb, cbias, 2048, 3072, 2048);

    // Wo transpose into region0 (hsb now dead)
    transpose_cast_kernel<<<dim3(64, 64), 256, 0, stream>>>(Wo, woT, 2048, 2048, 0);

    // RoPE + layouts
    rope_kernel<<<2048, 256, 0, stream>>>(qkvb, Qrb, Krb, Vtb);

    // attention (writes attnb into region1; wqkvT dead)
    attn_kernel<<<dim3(32, 16), 256, 0, stream>>>(Qrb, Krb, Vtb, mg, attnb);

    // output projection -> d_out (f32)
    gemm_bf16<false><<<16 * 32, 256, 0, stream>>>(attnb, woT, (float*)d_out, nullptr, 2048, 2048, 2048);
}

// Round 3
// 332.127 us; speedup vs baseline: 1.0432x; 1.0432x over previous
//
#include <hip/hip_runtime.h>
#include <stdint.h>

typedef __attribute__((ext_vector_type(8))) short short8;
typedef __attribute__((ext_vector_type(4))) float f32x4;

#define S_LEN 2048
#define HID 2048
#define NH 16
#define NKV 4
#define DH 128
#define WINDOW 1024
#define SCALE 0.08838834764831845f

__device__ __forceinline__ unsigned short f2bf(float f) {
    unsigned int u = __float_as_uint(f);
    unsigned int r = (u + 0x7fffu + ((u >> 16) & 1u)) >> 16;
    return (unsigned short)r;
}

__device__ __forceinline__ void gload16(const void* g, void* l) {
    __builtin_amdgcn_global_load_lds((__attribute__((address_space(1))) void*)g,
                                     (__attribute__((address_space(3))) void*)l, 16, 0, 0);
}

// ---------------- prep kernels ----------------

__global__ __launch_bounds__(256) void cast4_kernel(const float* __restrict__ src,
                                                    unsigned short* __restrict__ dst, int n4) {
    int i = blockIdx.x * 256 + threadIdx.x;
    if (i < n4) {
        float4 v = ((const float4*)src)[i];
        ushort4 o;
        o.x = f2bf(v.x); o.y = f2bf(v.y); o.z = f2bf(v.z); o.w = f2bf(v.w);
        ((ushort4*)dst)[i] = o;
    }
}

__global__ __launch_bounds__(256) void build_bias_kernel(const float* __restrict__ bq,
                                                         const float* __restrict__ bk,
                                                         const float* __restrict__ bv,
                                                         float* __restrict__ cbias) {
    int i = blockIdx.x * 256 + threadIdx.x;
    if (i < 3072) {
        float v;
        if (i < 2048) v = bq[i];
        else if (i < 2560) v = bk[i - 2048];
        else v = bv[i - 2560];
        cbias[i] = v;
    }
}

__global__ __launch_bounds__(256) void zero_kernel(float4* __restrict__ p, int n4) {
    int i = blockIdx.x * 256 + threadIdx.x;
    int stride = gridDim.x * 256;
    for (; i < n4; i += stride) p[i] = (float4){0.f, 0.f, 0.f, 0.f};
}

// src: K x N (f32), dst: (N x K) bf16 at row offset rowoff, row stride K
__global__ __launch_bounds__(256) void transpose_cast_kernel(const float* __restrict__ src,
                                                             unsigned short* __restrict__ dst,
                                                             int N, int K, int rowoff) {
    __shared__ unsigned short t[32][33];
    int n0 = blockIdx.x * 32, k0 = blockIdx.y * 32;
    int c = threadIdx.x & 31, r8 = threadIdx.x >> 5;
#pragma unroll
    for (int i = 0; i < 4; i++) {
        int r = r8 + i * 8;
        t[r][c] = f2bf(src[(size_t)(k0 + r) * N + n0 + c]);
    }
    __syncthreads();
#pragma unroll
    for (int i = 0; i < 4; i++) {
        int r = r8 + i * 8;
        dst[(size_t)(rowoff + n0 + r) * K + k0 + c] = t[c][r];
    }
}

// ---------------- GEMM (split-K): C[M,N] += A[M,ksub] * Bt[N,ksub]^T (+bias) --------
// 128x128 tile, BK=32, double-buffered global_load_lds staging, f32 atomic epilogue.

__global__ __launch_bounds__(256) void gemm_sk(const unsigned short* __restrict__ A,
                                               const unsigned short* __restrict__ Bt,
                                               float* __restrict__ C,
                                               const float* __restrict__ bias,
                                               int M, int N, int K, int split) {
    __shared__ unsigned short Al[2][128 * 32];
    __shared__ unsigned short Bl[2][128 * 32];
    const int tid = threadIdx.x;
    const int lane = tid & 63;
    const int w = tid >> 6;
    const int nbn = N >> 7;
    const int bm = blockIdx.x / nbn, bn = blockIdx.x % nbn;
    const int m0 = bm << 7, n0 = bn << 7;
    const int wr = w >> 1, wc = w & 1;
    const int Ksub = K / split;
    const int kbase = blockIdx.y * Ksub;

    const int lin0 = tid * 16;
    const int r0 = lin0 >> 6, b0 = lin0 & 63;
    const int lin1 = 4096 + tid * 16;
    const int r1 = lin1 >> 6, b1 = lin1 & 63;
    const size_t Kb = (size_t)K * 2;

    const char* Ab = (const char*)A + (size_t)m0 * Kb + (size_t)kbase * 2;
    const char* Bb = (const char*)Bt + (size_t)n0 * Kb + (size_t)kbase * 2;
    char* Al0 = (char*)&Al[0][0];
    char* Bl0 = (char*)&Bl[0][0];
    const int wb = w * 1024;

    auto stage = [&](int buf, int kt) {
        const char* Ak = Ab + kt * 64;
        const char* Bk = Bb + kt * 64;
        char* Ad = Al0 + buf * 8192;
        char* Bd = Bl0 + buf * 8192;
        gload16(Ak + (size_t)r0 * Kb + b0, Ad + wb);
        gload16(Ak + (size_t)r1 * Kb + b1, Ad + 4096 + wb);
        gload16(Bk + (size_t)r0 * Kb + b0, Bd + wb);
        gload16(Bk + (size_t)r1 * Kb + b1, Bd + 4096 + wb);
    };

    f32x4 acc[4][4] = {};
    const int NT = Ksub >> 5;
    stage(0, 0);
    for (int kt = 0; kt < NT; ++kt) {
        __syncthreads();
        if (kt + 1 < NT) stage((kt + 1) & 1, kt + 1);
        const char* Ar = (const char*)&Al[kt & 1][0];
        const char* Br = (const char*)&Bl[kt & 1][0];
        const int ko = (lane >> 4) * 16;
        short8 af[4], bfr[4];
#pragma unroll
        for (int m = 0; m < 4; m++)
            af[m] = *(const short8*)(Ar + (wr * 64 + m * 16 + (lane & 15)) * 64 + ko);
#pragma unroll
        for (int n = 0; n < 4; n++)
            bfr[n] = *(const short8*)(Br + (wc * 64 + n * 16 + (lane & 15)) * 64 + ko);
        __builtin_amdgcn_s_setprio(1);
#pragma unroll
        for (int m = 0; m < 4; m++)
#pragma unroll
            for (int n = 0; n < 4; n++)
                acc[m][n] = __builtin_amdgcn_mfma_f32_16x16x32_bf16(af[m], bfr[n], acc[m][n], 0, 0, 0);
        __builtin_amdgcn_s_setprio(0);
        __syncthreads();
    }

    const bool addb = (bias != nullptr) && (blockIdx.y == 0);
#pragma unroll
    for (int m = 0; m < 4; m++) {
        const int row = m0 + wr * 64 + m * 16 + (lane >> 4) * 4;
#pragma unroll
        for (int n = 0; n < 4; n++) {
            const int col = n0 + wc * 64 + n * 16 + (lane & 15);
            const float badd = addb ? bias[col] : 0.f;
            float* Cp = C + (size_t)row * N + col;
#pragma unroll
            for (int r = 0; r < 4; r++)
                unsafeAtomicAdd(Cp + (size_t)r * N, acc[m][n][r] + badd);
        }
    }
}

// ---------------- RoPE + layout ----------------
// qkv: [S][3072] f32  ->  Qr [16][S][128], Kr [4][S][128], Vt [4][128][S] (bf16)
__global__ __launch_bounds__(256) void rope_kernel(const float* __restrict__ qkv,
                                                   unsigned short* __restrict__ Qr,
                                                   unsigned short* __restrict__ Kr,
                                                   unsigned short* __restrict__ Vt) {
    int s = blockIdx.x, tid = threadIdx.x;
    __shared__ float cs[64], sn[64];
    if (tid < 64) {
        float inv = __expf(-(float)tid * (logf(10000.f) / 64.f));
        float ang = (float)s * inv;
        float si, co;
        sincosf(ang, &si, &co);
        cs[tid] = co;
        sn[tid] = si;
    }
    __syncthreads();
    const float* row = qkv + (size_t)s * 3072;
#pragma unroll
    for (int it = 0; it < 8; ++it) {
        int j = tid + it * 256;
        int h = j >> 7, d = j & 127, f = d & 63;
        float x = row[j];
        float other = row[(j & ~127) + (d ^ 64)];
        float v = (d < 64) ? x * cs[f] - other * sn[f] : x * cs[f] + other * sn[f];
        Qr[((size_t)h * S_LEN + s) * 128 + d] = f2bf(v);
    }
#pragma unroll
    for (int it = 0; it < 2; ++it) {
        int j = tid + it * 256;
        int kvh = j >> 7, d = j & 127, f = d & 63;
        float x = row[2048 + j];
        float other = row[2048 + (j & ~127) + (d ^ 64)];
        float v = (d < 64) ? x * cs[f] - other * sn[f] : x * cs[f] + other * sn[f];
        Kr[((size_t)kvh * S_LEN + s) * 128 + d] = f2bf(v);
        float vv = row[2560 + j];
        Vt[((size_t)kvh * 128 + d) * S_LEN + s] = f2bf(vv);
    }
}

// ---------------- flash attention, sliding window, GQA ----------------
// K/V double-buffered in LDS via global_load_lds; interior-tile fast path;
// defer-max rescale skip; hoisted P fragments; setprio around MFMA.

__global__ __launch_bounds__(256) void attn_kernel(const unsigned short* __restrict__ Qr,
                                                   const unsigned short* __restrict__ Kr,
                                                   const unsigned short* __restrict__ Vt,
                                                   const float* __restrict__ mg,
                                                   unsigned short* __restrict__ Ao) {
    __shared__ unsigned short Kl[2][64 * 128];  // swizzled rows of 256B
    __shared__ unsigned short Vl[2][128 * 64];  // swizzled rows of 128B
    __shared__ unsigned short Pl[4][16 * 64];   // per-wave, swizzled rows of 128B
    const int tid = threadIdx.x, lane = tid & 63, w = tid >> 6;
    const int h = blockIdx.y, qt = blockIdx.x;
    const int kvh = h >> 2;
    const int q0 = qt * 64;
    const int lo = lane & 15, hi = lane >> 4;

    const unsigned short* Qb =
        Qr + ((size_t)h * S_LEN + q0 + w * 16 + lo) * 128 + hi * 8;
    short8 qf[4];
#pragma unroll
    for (int ks = 0; ks < 4; ++ks) qf[ks] = *(const short8*)(Qb + ks * 32);

    const float gate = 1.f / (1.f + __expf(-mg[h]));
    const float fac = 1.f - gate;

    float mrow[4] = {-INFINITY, -INFINITY, -INFINITY, -INFINITY};
    float lrow[4] = {0.f, 0.f, 0.f, 0.f};
    f32x4 o[8] = {};

    const char* Kg = (const char*)(Kr + (size_t)kvh * S_LEN * 128);
    const char* Vg = (const char*)(Vt + (size_t)kvh * 128 * S_LEN);
    char* Klb = (char*)&Kl[0][0];
    char* Vlb = (char*)&Vl[0][0];
    const int wb = w * 1024;

    auto stage = [&](int buf, int kt) {
        const int k0 = kt * 64;
#pragma unroll
        for (int iss = 0; iss < 4; ++iss) {
            int lin = iss * 4096 + tid * 16;
            int row = lin >> 8;
            int chunk = (lin >> 4) & 15;
            gload16(Kg + (size_t)(k0 + row) * 256 + ((chunk ^ (row & 7)) << 4),
                    Klb + buf * 16384 + iss * 4096 + wb);
            int d = lin >> 7;
            int vchunk = (lin >> 4) & 7;
            gload16(Vg + (size_t)d * (S_LEN * 2) + (size_t)k0 * 2 + ((vchunk ^ (d & 7)) << 4),
                    Vlb + buf * 16384 + iss * 4096 + wb);
        }
    };

    const int qmin = q0 + w * 16;  // this wave's lowest q-row
    const int t0 = (q0 >= 1023) ? (q0 - 1023) >> 6 : 0;
    stage(0, t0);
    for (int kt = t0; kt <= qt; ++kt) {
        __syncthreads();
        if (kt < qt) stage((kt - t0 + 1) & 1, kt + 1);
        const int buf = (kt - t0) & 1;
        const int k0 = kt * 64;
        const char* Kb = Klb + buf * 16384;
        const char* Vb = Vlb + buf * 16384;

        // QK^T : per wave 16 q-rows x 64 k-cols
        f32x4 sc[4];
        __builtin_amdgcn_s_setprio(1);
#pragma unroll
        for (int t = 0; t < 4; t++) {
            sc[t] = (f32x4){0.f, 0.f, 0.f, 0.f};
            const int krow = t * 16 + lo;
#pragma unroll
            for (int ks = 0; ks < 4; ks++) {
                const int chunk = ks * 4 + hi;
                short8 kf = *(const short8*)(Kb + krow * 256 + ((chunk ^ (krow & 7)) << 4));
                sc[t] = __builtin_amdgcn_mfma_f32_16x16x32_bf16(qf[ks], kf, sc[t], 0, 0, 0);
            }
        }
        __builtin_amdgcn_s_setprio(0);

        // scores + mask (wave-uniform interior fast path)
        const bool full = (k0 + 63 <= qmin) && (k0 >= qmin + 15 - (WINDOW - 1));
        float ps[4][4];
        float mt[4];
        if (full) {
#pragma unroll
            for (int r = 0; r < 4; r++) {
                float m0v = -INFINITY;
#pragma unroll
                for (int t = 0; t < 4; t++) {
                    float sv = sc[t][r] * SCALE;
                    ps[t][r] = sv;
                    m0v = fmaxf(m0v, sv);
                }
                mt[r] = m0v;
            }
        } else {
#pragma unroll
            for (int r = 0; r < 4; r++) {
                const int q = qmin + hi * 4 + r;
                float m0v = -INFINITY;
#pragma unroll
                for (int t = 0; t < 4; t++) {
                    const int k = k0 + t * 16 + lo;
                    const bool valid = (k <= q) && (q - k < WINDOW);
                    float sv = valid ? sc[t][r] * SCALE : -INFINITY;
                    ps[t][r] = sv;
                    m0v = fmaxf(m0v, sv);
                }
                mt[r] = m0v;
            }
        }

        // online softmax with defer-max (THR=8)
        float alpha[4];
        bool need = false;
#pragma unroll
        for (int r = 0; r < 4; r++) {
#pragma unroll
            for (int off = 1; off < 16; off <<= 1) mt[r] = fmaxf(mt[r], __shfl_xor(mt[r], off, 64));
            const float mo = mrow[r];
            const float mn = (mt[r] > mo + 8.f) ? mt[r] : mo;
            const bool resc = (mn != mo);
            alpha[r] = resc ? __expf(mo - mn) : 1.f;
            need = need || resc;
            mrow[r] = mn;
            const float mn_e = (mn == -INFINITY) ? 0.f : mn;
            float ls = 0.f;
#pragma unroll
            for (int t = 0; t < 4; t++) {
                float p = __expf(ps[t][r] - mn_e);
                ps[t][r] = p;
                ls += p;
            }
#pragma unroll
            for (int off = 1; off < 16; off <<= 1) ls += __shfl_xor(ls, off, 64);
            lrow[r] = lrow[r] * alpha[r] + ls;
        }

        // P -> LDS (bf16, swizzled 128B rows)
        char* Pw = (char*)&Pl[w][0];
#pragma unroll
        for (int r = 0; r < 4; r++) {
            const int prow = hi * 4 + r;
#pragma unroll
            for (int t = 0; t < 4; t++) {
                const int col = t * 16 + lo;
                const int chunk = col >> 3;
                *(unsigned short*)(Pw + prow * 128 + ((chunk ^ (prow & 7)) << 4) + (col & 7) * 2) =
                    f2bf(ps[t][r]);
            }
        }
        asm volatile("s_waitcnt lgkmcnt(0)" ::: "memory");
        __builtin_amdgcn_sched_barrier(0);

        // rescale O (skipped when all rows deferred)
        if (__any(need)) {
#pragma unroll
            for (int n = 0; n < 8; n++)
#pragma unroll
                for (int r = 0; r < 4; r++) o[n][r] *= alpha[r];
        }

        // hoisted P fragments (same for all n)
        short8 pa[2];
#pragma unroll
        for (int ks = 0; ks < 2; ++ks) {
            const int chunk = ks * 4 + hi;
            pa[ks] = *(const short8*)(Pw + lo * 128 + ((chunk ^ (lo & 7)) << 4));
        }

        // PV
        __builtin_amdgcn_s_setprio(1);
#pragma unroll
        for (int n = 0; n < 8; n++) {
            const int d = n * 16 + lo;
#pragma unroll
            for (int ks = 0; ks < 2; ++ks) {
                const int chunk = ks * 4 + hi;
                short8 vbf = *(const short8*)(Vb + d * 128 + ((chunk ^ (d & 7)) << 4));
                o[n] = __builtin_amdgcn_mfma_f32_16x16x32_bf16(pa[ks], vbf, o[n], 0, 0, 0);
            }
        }
        __builtin_amdgcn_s_setprio(0);
        __syncthreads();
    }

    // epilogue: out = (1-gate) * local / l
#pragma unroll
    for (int r = 0; r < 4; r++) {
        const int s = q0 + w * 16 + hi * 4 + r;
        const float inv = fac / lrow[r];
#pragma unroll
        for (int n = 0; n < 8; n++) {
            const int d = n * 16 + lo;
            Ao[(size_t)s * 2048 + h * 128 + d] = f2bf(o[n][r] * inv);
        }
    }
}

// ---------------- launch ----------------

extern "C" void kernel_launch(void* const* d_in, const int* in_sizes, int n_in,
                              void* d_out, int out_size, void* d_ws, size_t ws_size,
                              hipStream_t stream) {
    const float* hs = (const float*)d_in[0];
    const float* Wq = (const float*)d_in[1];
    const float* bq = (const float*)d_in[2];
    const float* Wk = (const float*)d_in[3];
    const float* bk = (const float*)d_in[4];
    const float* Wv = (const float*)d_in[5];
    const float* bv = (const float*)d_in[6];
    const float* Wo = (const float*)d_in[7];
    const float* mg = (const float*)d_in[8];

    char* ws = (char*)d_ws;
    // region layout (bytes)
    unsigned short* hsb   = (unsigned short*)(ws + 0);          // 8 MB, dead after QKV gemm
    unsigned short* woT   = (unsigned short*)(ws + 0);          // reuses hsb region (8 MB)
    unsigned short* wqkvT = (unsigned short*)(ws + 8388608);    // 12 MB, dead after QKV gemm
    unsigned short* attnb = (unsigned short*)(ws + 8388608);    // reuses wqkvT region (8 MB)
    float*          qkvf  = (float*)(ws + 20971520);            // 25.2 MB (f32), dead after rope
    unsigned short* Qrb   = (unsigned short*)(ws + 46137344);   // 8 MB
    unsigned short* Krb   = (unsigned short*)(ws + 54525952);   // 2 MB
    unsigned short* Vtb   = (unsigned short*)(ws + 56623104);   // 2 MB
    float*          cbias = (float*)(ws + 58720256);            // 12 KB

    // prep
    cast4_kernel<<<4096, 256, 0, stream>>>(hs, hsb, 1048576);
    build_bias_kernel<<<12, 256, 0, stream>>>(bq, bk, bv, cbias);
    transpose_cast_kernel<<<dim3(64, 64), 256, 0, stream>>>(Wq, wqkvT, 2048, 2048, 0);
    transpose_cast_kernel<<<dim3(16, 64), 256, 0, stream>>>(Wk, wqkvT, 512, 2048, 2048);
    transpose_cast_kernel<<<dim3(16, 64), 256, 0, stream>>>(Wv, wqkvT, 512, 2048, 2560);
    zero_kernel<<<2048, 256, 0, stream>>>((float4*)qkvf, 1572864);

    // QKV projection: [2048,2048] x [2048,3072] (+bias), split-K=2, atomic f32
    gemm_sk<<<dim3(16 * 24, 2), 256, 0, stream>>>(hsb, wqkvT, qkvf, cbias, 2048, 3072, 2048, 2);

    // Wo transpose into region0 (hsb now dead)
    transpose_cast_kernel<<<dim3(64, 64), 256, 0, stream>>>(Wo, woT, 2048, 2048, 0);

    // RoPE + layouts
    rope_kernel<<<2048, 256, 0, stream>>>(qkvf, Qrb, Krb, Vtb);

    // attention (writes attnb into region1; wqkvT dead)
    attn_kernel<<<dim3(32, 16), 256, 0, stream>>>(Qrb, Krb, Vtb, mg, attnb);

    // output projection -> d_out (f32), split-K=4, atomic
    zero_kernel<<<2048, 256, 0, stream>>>((float4*)d_out, 1048576);
    gemm_sk<<<dim3(16 * 16, 4), 256, 0, stream>>>(attnb, woT, (float*)d_out, nullptr, 2048, 2048, 2048, 4);
}

// Round 4
// 254.466 us; speedup vs baseline: 1.3616x; 1.3052x over previous
//
#include <hip/hip_runtime.h>
#include <stdint.h>

typedef __attribute__((ext_vector_type(8))) short short8;
typedef __attribute__((ext_vector_type(4))) float f32x4;

#define S_LEN 2048
#define HID 2048
#define NH 16
#define NKV 4
#define DH 128
#define WINDOW 1024
#define SCALE 0.08838834764831845f

__device__ __forceinline__ unsigned short f2bf(float f) {
    unsigned int u = __float_as_uint(f);
    unsigned int r = (u + 0x7fffu + ((u >> 16) & 1u)) >> 16;
    return (unsigned short)r;
}

__device__ __forceinline__ float bf2f(unsigned short u) {
    return __uint_as_float((unsigned int)u << 16);
}

__device__ __forceinline__ void gload16(const void* g, void* l) {
    __builtin_amdgcn_global_load_lds((__attribute__((address_space(1))) void*)g,
                                     (__attribute__((address_space(3))) void*)l, 16, 0, 0);
}

// ---------------- prep kernels ----------------

__global__ __launch_bounds__(256) void cast4_kernel(const float* __restrict__ src,
                                                    unsigned short* __restrict__ dst, int n4) {
    int i = blockIdx.x * 256 + threadIdx.x;
    if (i < n4) {
        float4 v = ((const float4*)src)[i];
        ushort4 o;
        o.x = f2bf(v.x); o.y = f2bf(v.y); o.z = f2bf(v.z); o.w = f2bf(v.w);
        ((ushort4*)dst)[i] = o;
    }
}

__global__ __launch_bounds__(256) void build_bias_kernel(const float* __restrict__ bq,
                                                         const float* __restrict__ bk,
                                                         const float* __restrict__ bv,
                                                         float* __restrict__ cbias) {
    int i = blockIdx.x * 256 + threadIdx.x;
    if (i < 3072) {
        float v;
        if (i < 2048) v = bq[i];
        else if (i < 2560) v = bk[i - 2048];
        else v = bv[i - 2560];
        cbias[i] = v;
    }
}

// src: K x N (f32), dst: (N x K) bf16 at row offset rowoff, row stride K
__global__ __launch_bounds__(256) void transpose_cast_kernel(const float* __restrict__ src,
                                                             unsigned short* __restrict__ dst,
                                                             int N, int K, int rowoff) {
    __shared__ unsigned short t[32][33];
    int n0 = blockIdx.x * 32, k0 = blockIdx.y * 32;
    int c = threadIdx.x & 31, r8 = threadIdx.x >> 5;
#pragma unroll
    for (int i = 0; i < 4; i++) {
        int r = r8 + i * 8;
        t[r][c] = f2bf(src[(size_t)(k0 + r) * N + n0 + c]);
    }
    __syncthreads();
#pragma unroll
    for (int i = 0; i < 4; i++) {
        int r = r8 + i * 8;
        dst[(size_t)(rowoff + n0 + r) * K + k0 + c] = t[c][r];
    }
}

// ---------------- GEMM: C[M,N] = A[M,K] * Bt[N,K]^T (+bias) ----------------
// 128x128 tile, BK=32, triple-buffered LDS, depth-2 global_load_lds prefetch,
// counted vmcnt (T3/T4), both-sides chunk swizzle (T2), setprio (T5).

template <bool BF16OUT>
__global__ __launch_bounds__(256) void gemm_pipe(const unsigned short* __restrict__ A,
                                                 const unsigned short* __restrict__ Bt,
                                                 void* __restrict__ Cv,
                                                 const float* __restrict__ bias,
                                                 int M, int N, int K) {
    __shared__ unsigned short Al[3][128 * 32];
    __shared__ unsigned short Bl[3][128 * 32];
    const int tid = threadIdx.x, lane = tid & 63, w = tid >> 6;
    const int lo = lane & 15, hi = lane >> 4;
    const int nbn = N >> 7;
    // bijective XCD swizzle (grid % 8 == 0 for all our launches)
    const int nwg8 = gridDim.x >> 3;
    const int wg = (blockIdx.x & 7) * nwg8 + (blockIdx.x >> 3);
    const int bm = wg / nbn, bn = wg % nbn;
    const int m0 = bm << 7, n0 = bn << 7;
    const int wr = w >> 1, wc = w & 1;
    const size_t Kb = (size_t)K * 2;

    const char* Ab = (const char*)A + (size_t)m0 * Kb;
    const char* Bb = (const char*)Bt + (size_t)n0 * Kb;
    char* Alb = (char*)&Al[0][0];
    char* Blb = (char*)&Bl[0][0];

    // staging geometry: 2 groups x 4096B per operand; LDS dest linear,
    // global source chunk-swizzled (inverse of the read swizzle)
    const int L0 = tid * 16;
    const int L1 = 4096 + tid * 16;
    const int r0 = L0 >> 6, r1 = L1 >> 6;
    const size_t go0 = (size_t)r0 * Kb + ((((L0 >> 4) & 3) ^ (r0 & 3)) << 4);
    const size_t go1 = (size_t)r1 * Kb + ((((L1 >> 4) & 3) ^ (r1 & 3)) << 4);

    auto stage = [&](int buf, int kt) {
        const char* Ak = Ab + (size_t)kt * 64;
        const char* Bk = Bb + (size_t)kt * 64;
        char* Ad = Alb + buf * 8192;
        char* Bd = Blb + buf * 8192;
        gload16(Ak + go0, Ad + L0);
        gload16(Ak + go1, Ad + L1);
        gload16(Bk + go0, Bd + L0);
        gload16(Bk + go1, Bd + L1);
    };

    f32x4 acc[4][4] = {};
    const int NT = K >> 5;
    const int swz = (hi ^ (lo & 3)) << 4;  // row&3 == lo&3 for all fragment rows

    stage(0, 0);
    stage(1, 1);
    int buf = 0, nstage = 2;  // next stage target = nstage % 3
    for (int kt = 0; kt < NT; ++kt) {
        if (kt < NT - 1)
            asm volatile("s_waitcnt vmcnt(4)" ::: "memory");
        else
            asm volatile("s_waitcnt vmcnt(0)" ::: "memory");
        __builtin_amdgcn_s_barrier();

        const char* Ar = Alb + buf * 8192;
        const char* Br = Blb + buf * 8192;
        short8 af[4], bfr[4];
#pragma unroll
        for (int m = 0; m < 4; m++)
            af[m] = *(const short8*)(Ar + (wr * 64 + m * 16 + lo) * 64 + swz);
#pragma unroll
        for (int n = 0; n < 4; n++)
            bfr[n] = *(const short8*)(Br + (wc * 64 + n * 16 + lo) * 64 + swz);
        asm volatile("s_waitcnt lgkmcnt(0)" ::: "memory");
        __builtin_amdgcn_s_barrier();

        if (kt + 2 < NT) {
            int bst = nstage;
            bst = (bst >= 3) ? bst - 3 : bst;
            stage(bst, kt + 2);
            nstage = bst + 1;
        }
        __builtin_amdgcn_sched_barrier(0);

        __builtin_amdgcn_s_setprio(1);
#pragma unroll
        for (int m = 0; m < 4; m++)
#pragma unroll
            for (int n = 0; n < 4; n++)
                acc[m][n] = __builtin_amdgcn_mfma_f32_16x16x32_bf16(af[m], bfr[n], acc[m][n], 0, 0, 0);
        __builtin_amdgcn_s_setprio(0);

        buf = (buf == 2) ? 0 : buf + 1;
    }

#pragma unroll
    for (int m = 0; m < 4; m++) {
        const int row = m0 + wr * 64 + m * 16 + hi * 4;
#pragma unroll
        for (int n = 0; n < 4; n++) {
            const int col = n0 + wc * 64 + n * 16 + lo;
            const float badd = bias ? bias[col] : 0.f;
#pragma unroll
            for (int r = 0; r < 4; r++) {
                const float v = acc[m][n][r] + badd;
                if constexpr (BF16OUT)
                    ((unsigned short*)Cv)[(size_t)(row + r) * N + col] = f2bf(v);
                else
                    ((float*)Cv)[(size_t)(row + r) * N + col] = v;
            }
        }
    }
}

// ---------------- RoPE (Q,K only) ----------------
// qkv: [S][3072] bf16  ->  Qr [16][S][128], Kr [4][S][128] (bf16)
__global__ __launch_bounds__(256) void rope_qk_kernel(const unsigned short* __restrict__ qkv,
                                                      unsigned short* __restrict__ Qr,
                                                      unsigned short* __restrict__ Kr) {
    int s = blockIdx.x, tid = threadIdx.x;
    __shared__ float cs[64], sn[64];
    if (tid < 64) {
        float inv = __expf(-(float)tid * (logf(10000.f) / 64.f));
        float ang = (float)s * inv;
        float si, co;
        sincosf(ang, &si, &co);
        cs[tid] = co;
        sn[tid] = si;
    }
    __syncthreads();
    const unsigned short* row = qkv + (size_t)s * 3072;
#pragma unroll
    for (int it = 0; it < 8; ++it) {
        int j = tid + it * 256;
        int h = j >> 7, d = j & 127, f = d & 63;
        float x = bf2f(row[j]);
        float other = bf2f(row[(j & ~127) + (d ^ 64)]);
        float v = (d < 64) ? x * cs[f] - other * sn[f] : x * cs[f] + other * sn[f];
        Qr[((size_t)h * S_LEN + s) * 128 + d] = f2bf(v);
    }
#pragma unroll
    for (int it = 0; it < 2; ++it) {
        int j = tid + it * 256;
        int kvh = j >> 7, d = j & 127, f = d & 63;
        float x = bf2f(row[2048 + j]);
        float other = bf2f(row[2048 + (j & ~127) + (d ^ 64)]);
        float v = (d < 64) ? x * cs[f] - other * sn[f] : x * cs[f] + other * sn[f];
        Kr[((size_t)kvh * S_LEN + s) * 128 + d] = f2bf(v);
    }
}

// ---------------- V transpose: qkv [S][3072] -> Vt [4][128][S] ----------------
// LDS transpose, coalesced 16B on both sides.
__global__ __launch_bounds__(256) void transpose_v_kernel(const unsigned short* __restrict__ qkv,
                                                          unsigned short* __restrict__ Vt) {
    __shared__ unsigned short t[128][132];
    const int s0 = blockIdx.x * 128;
    const int kvh = blockIdx.y;
    const int tx = threadIdx.x & 15, ty = threadIdx.x >> 4;
    const unsigned short* src = qkv + 2560 + kvh * 128;
#pragma unroll
    for (int i = 0; i < 8; i++) {
        const int sl = ty + i * 16;
        short8 v = *(const short8*)(src + (size_t)(s0 + sl) * 3072 + tx * 8);
#pragma unroll
        for (int j = 0; j < 8; j++) t[sl][tx * 8 + j] = v[j];
    }
    __syncthreads();
    unsigned short* dst = Vt + (size_t)kvh * 128 * S_LEN + s0;
#pragma unroll
    for (int i = 0; i < 8; i++) {
        const int d = ty + i * 16;
        short8 v;
#pragma unroll
        for (int j = 0; j < 8; j++) v[j] = t[tx * 8 + j][d];
        *(short8*)(dst + (size_t)d * S_LEN + tx * 8) = v;
    }
}

// ---------------- flash attention, sliding window, GQA ----------------

__global__ __launch_bounds__(256) void attn_kernel(const unsigned short* __restrict__ Qr,
                                                   const unsigned short* __restrict__ Kr,
                                                   const unsigned short* __restrict__ Vt,
                                                   const float* __restrict__ mg,
                                                   unsigned short* __restrict__ Ao) {
    __shared__ unsigned short Kl[2][64 * 128];  // swizzled rows of 256B
    __shared__ unsigned short Vl[2][128 * 64];  // swizzled rows of 128B
    __shared__ unsigned short Pl[4][16 * 64];   // per-wave, swizzled rows of 128B
    const int tid = threadIdx.x, lane = tid & 63, w = tid >> 6;
    const int h = blockIdx.y, qt = blockIdx.x;
    const int kvh = h >> 2;
    const int q0 = qt * 64;
    const int lo = lane & 15, hi = lane >> 4;

    const unsigned short* Qb =
        Qr + ((size_t)h * S_LEN + q0 + w * 16 + lo) * 128 + hi * 8;
    short8 qf[4];
#pragma unroll
    for (int ks = 0; ks < 4; ++ks) qf[ks] = *(const short8*)(Qb + ks * 32);

    const float gate = 1.f / (1.f + __expf(-mg[h]));
    const float fac = 1.f - gate;

    float mrow[4] = {-INFINITY, -INFINITY, -INFINITY, -INFINITY};
    float lrow[4] = {0.f, 0.f, 0.f, 0.f};
    f32x4 o[8] = {};

    const char* Kg = (const char*)(Kr + (size_t)kvh * S_LEN * 128);
    const char* Vg = (const char*)(Vt + (size_t)kvh * 128 * S_LEN);
    char* Klb = (char*)&Kl[0][0];
    char* Vlb = (char*)&Vl[0][0];
    const int wb = w * 1024;

    auto stage = [&](int buf, int kt) {
        const int k0 = kt * 64;
#pragma unroll
        for (int iss = 0; iss < 4; ++iss) {
            int lin = iss * 4096 + tid * 16;
            int row = lin >> 8;
            int chunk = (lin >> 4) & 15;
            gload16(Kg + (size_t)(k0 + row) * 256 + ((chunk ^ (row & 7)) << 4),
                    Klb + buf * 16384 + iss * 4096 + wb);
            int d = lin >> 7;
            int vchunk = (lin >> 4) & 7;
            gload16(Vg + (size_t)d * (S_LEN * 2) + (size_t)k0 * 2 + ((vchunk ^ (d & 7)) << 4),
                    Vlb + buf * 16384 + iss * 4096 + wb);
        }
    };

    const int qmin = q0 + w * 16;  // this wave's lowest q-row
    const int t0 = (q0 >= 1023) ? (q0 - 1023) >> 6 : 0;
    stage(0, t0);
    for (int kt = t0; kt <= qt; ++kt) {
        __syncthreads();
        if (kt < qt) stage((kt - t0 + 1) & 1, kt + 1);
        const int buf = (kt - t0) & 1;
        const int k0 = kt * 64;
        const char* Kb = Klb + buf * 16384;
        const char* Vb = Vlb + buf * 16384;

        // QK^T : per wave 16 q-rows x 64 k-cols
        f32x4 sc[4];
        __builtin_amdgcn_s_setprio(1);
#pragma unroll
        for (int t = 0; t < 4; t++) {
            sc[t] = (f32x4){0.f, 0.f, 0.f, 0.f};
            const int krow = t * 16 + lo;
#pragma unroll
            for (int ks = 0; ks < 4; ks++) {
                const int chunk = ks * 4 + hi;
                short8 kf = *(const short8*)(Kb + krow * 256 + ((chunk ^ (krow & 7)) << 4));
                sc[t] = __builtin_amdgcn_mfma_f32_16x16x32_bf16(qf[ks], kf, sc[t], 0, 0, 0);
            }
        }
        __builtin_amdgcn_s_setprio(0);

        // scores + mask (wave-uniform interior fast path)
        const bool full = (k0 + 63 <= qmin) && (k0 >= qmin + 15 - (WINDOW - 1));
        float ps[4][4];
        float mt[4];
        if (full) {
#pragma unroll
            for (int r = 0; r < 4; r++) {
                float m0v = -INFINITY;
#pragma unroll
                for (int t = 0; t < 4; t++) {
                    float sv = sc[t][r] * SCALE;
                    ps[t][r] = sv;
                    m0v = fmaxf(m0v, sv);
                }
                mt[r] = m0v;
            }
        } else {
#pragma unroll
            for (int r = 0; r < 4; r++) {
                const int q = qmin + hi * 4 + r;
                float m0v = -INFINITY;
#pragma unroll
                for (int t = 0; t < 4; t++) {
                    const int k = k0 + t * 16 + lo;
                    const bool valid = (k <= q) && (q - k < WINDOW);
                    float sv = valid ? sc[t][r] * SCALE : -INFINITY;
                    ps[t][r] = sv;
                    m0v = fmaxf(m0v, sv);
                }
                mt[r] = m0v;
            }
        }

        // online softmax with defer-max (THR=8)
        float alpha[4];
        bool need = false;
#pragma unroll
        for (int r = 0; r < 4; r++) {
#pragma unroll
            for (int off = 1; off < 16; off <<= 1) mt[r] = fmaxf(mt[r], __shfl_xor(mt[r], off, 64));
            const float mo = mrow[r];
            const float mn = (mt[r] > mo + 8.f) ? mt[r] : mo;
            const bool resc = (mn != mo);
            alpha[r] = resc ? __expf(mo - mn) : 1.f;
            need = need || resc;
            mrow[r] = mn;
            const float mn_e = (mn == -INFINITY) ? 0.f : mn;
            float ls = 0.f;
#pragma unroll
            for (int t = 0; t < 4; t++) {
                float p = __expf(ps[t][r] - mn_e);
                ps[t][r] = p;
                ls += p;
            }
#pragma unroll
            for (int off = 1; off < 16; off <<= 1) ls += __shfl_xor(ls, off, 64);
            lrow[r] = lrow[r] * alpha[r] + ls;
        }

        // P -> LDS (bf16, swizzled 128B rows)
        char* Pw = (char*)&Pl[w][0];
#pragma unroll
        for (int r = 0; r < 4; r++) {
            const int prow = hi * 4 + r;
#pragma unroll
            for (int t = 0; t < 4; t++) {
                const int col = t * 16 + lo;
                const int chunk = col >> 3;
                *(unsigned short*)(Pw + prow * 128 + ((chunk ^ (prow & 7)) << 4) + (col & 7) * 2) =
                    f2bf(ps[t][r]);
            }
        }
        asm volatile("s_waitcnt lgkmcnt(0)" ::: "memory");
        __builtin_amdgcn_sched_barrier(0);

        // rescale O (skipped when all rows deferred)
        if (__any(need)) {
#pragma unroll
            for (int n = 0; n < 8; n++)
#pragma unroll
                for (int r = 0; r < 4; r++) o[n][r] *= alpha[r];
        }

        // hoisted P fragments (same for all n)
        short8 pa[2];
#pragma unroll
        for (int ks = 0; ks < 2; ++ks) {
            const int chunk = ks * 4 + hi;
            pa[ks] = *(const short8*)(Pw + lo * 128 + ((chunk ^ (lo & 7)) << 4));
        }

        // PV
        __builtin_amdgcn_s_setprio(1);
#pragma unroll
        for (int n = 0; n < 8; n++) {
            const int d = n * 16 + lo;
#pragma unroll
            for (int ks = 0; ks < 2; ++ks) {
                const int chunk = ks * 4 + hi;
                short8 vbf = *(const short8*)(Vb + d * 128 + ((chunk ^ (d & 7)) << 4));
                o[n] = __builtin_amdgcn_mfma_f32_16x16x32_bf16(pa[ks], vbf, o[n], 0, 0, 0);
            }
        }
        __builtin_amdgcn_s_setprio(0);
        __syncthreads();
    }

    // epilogue: out = (1-gate) * local / l
#pragma unroll
    for (int r = 0; r < 4; r++) {
        const int s = q0 + w * 16 + hi * 4 + r;
        const float inv = fac / lrow[r];
#pragma unroll
        for (int n = 0; n < 8; n++) {
            const int d = n * 16 + lo;
            Ao[(size_t)s * 2048 + h * 128 + d] = f2bf(o[n][r] * inv);
        }
    }
}

// ---------------- launch ----------------

extern "C" void kernel_launch(void* const* d_in, const int* in_sizes, int n_in,
                              void* d_out, int out_size, void* d_ws, size_t ws_size,
                              hipStream_t stream) {
    const float* hs = (const float*)d_in[0];
    const float* Wq = (const float*)d_in[1];
    const float* bq = (const float*)d_in[2];
    const float* Wk = (const float*)d_in[3];
    const float* bk = (const float*)d_in[4];
    const float* Wv = (const float*)d_in[5];
    const float* bv = (const float*)d_in[6];
    const float* Wo = (const float*)d_in[7];
    const float* mg = (const float*)d_in[8];

    char* ws = (char*)d_ws;
    // region layout (bytes)
    unsigned short* hsb   = (unsigned short*)(ws + 0);          // 8 MB, dead after QKV gemm
    unsigned short* woT   = (unsigned short*)(ws + 0);          // reuses hsb region (8 MB)
    unsigned short* wqkvT = (unsigned short*)(ws + 8388608);    // 12 MB, dead after QKV gemm
    unsigned short* attnb = (unsigned short*)(ws + 8388608);    // reuses wqkvT region (8 MB)
    unsigned short* qkvb  = (unsigned short*)(ws + 20971520);   // 12.6 MB bf16
    unsigned short* Qrb   = (unsigned short*)(ws + 33554432);   // 8 MB
    unsigned short* Krb   = (unsigned short*)(ws + 41943040);   // 2 MB
    unsigned short* Vtb   = (unsigned short*)(ws + 44040192);   // 2 MB
    float*          cbias = (float*)(ws + 46137344);            // 12 KB

    // prep
    cast4_kernel<<<4096, 256, 0, stream>>>(hs, hsb, 1048576);
    build_bias_kernel<<<12, 256, 0, stream>>>(bq, bk, bv, cbias);
    transpose_cast_kernel<<<dim3(64, 64), 256, 0, stream>>>(Wq, wqkvT, 2048, 2048, 0);
    transpose_cast_kernel<<<dim3(16, 64), 256, 0, stream>>>(Wk, wqkvT, 512, 2048, 2048);
    transpose_cast_kernel<<<dim3(16, 64), 256, 0, stream>>>(Wv, wqkvT, 512, 2048, 2560);

    // QKV projection: [2048,2048] x [2048,3072] (+bias), bf16 out
    gemm_pipe<true><<<16 * 24, 256, 0, stream>>>(hsb, wqkvT, qkvb, cbias, 2048, 3072, 2048);

    // Wo transpose into region0 (hsb now dead)
    transpose_cast_kernel<<<dim3(64, 64), 256, 0, stream>>>(Wo, woT, 2048, 2048, 0);

    // RoPE + layouts
    rope_qk_kernel<<<2048, 256, 0, stream>>>(qkvb, Qrb, Krb);
    transpose_v_kernel<<<dim3(16, 4), 256, 0, stream>>>(qkvb, Vtb);

    // attention (writes attnb into region1; wqkvT dead)
    attn_kernel<<<dim3(32, 16), 256, 0, stream>>>(Qrb, Krb, Vtb, mg, attnb);

    // output projection -> d_out (f32)
    gemm_pipe<false><<<16 * 16, 256, 0, stream>>>(attnb, woT, (float*)d_out, nullptr, 2048, 2048, 2048);
}

// Round 5
// 235.137 us; speedup vs baseline: 1.4736x; 1.0822x over previous
//
#include <hip/hip_runtime.h>
#include <stdint.h>

typedef __attribute__((ext_vector_type(8))) short short8;
typedef __attribute__((ext_vector_type(4))) float f32x4;

#define S_LEN 2048
#define HID 2048
#define NH 16
#define NKV 4
#define DH 128
#define WINDOW 1024
#define SCALE 0.08838834764831845f

__device__ __forceinline__ unsigned short f2bf(float f) {
    unsigned int u = __float_as_uint(f);
    unsigned int r = (u + 0x7fffu + ((u >> 16) & 1u)) >> 16;
    return (unsigned short)r;
}

__device__ __forceinline__ void gload16(const void* g, void* l) {
    __builtin_amdgcn_global_load_lds((__attribute__((address_space(1))) void*)g,
                                     (__attribute__((address_space(3))) void*)l, 16, 0, 0);
}

// ---------------- fused prep kernel ----------------
// grid partition:
// [0,4096)        cast hs f32 -> bf16 (float4 granules)
// [4096,4608)     rope cos/sin tables [2048][64] f32
// [4608,4620)     bias concat
// [4620,8716)     transpose Wq  (64 x 64 tiles of 32)
// [8716,9740)     transpose Wk  (16 x 64)
// [9740,10764)    transpose Wv  (16 x 64)
// [10764,14860)   transpose Wo  (64 x 64)

__device__ __forceinline__ void tile_transpose(const float* __restrict__ src,
                                               unsigned short* __restrict__ dst,
                                               int N, int K, int rowoff, int idx, int nbx,
                                               unsigned short (*t)[33]) {
    const int nx = idx & (nbx - 1), ky = idx / nbx;
    const int n0 = nx * 32, k0 = ky * 32;
    const int c = threadIdx.x & 31, r8 = threadIdx.x >> 5;
#pragma unroll
    for (int i = 0; i < 4; i++) {
        int r = r8 + i * 8;
        t[r][c] = f2bf(src[(size_t)(k0 + r) * N + n0 + c]);
    }
    __syncthreads();
#pragma unroll
    for (int i = 0; i < 4; i++) {
        int r = r8 + i * 8;
        dst[(size_t)(rowoff + n0 + r) * K + k0 + c] = t[c][r];
    }
}

__global__ __launch_bounds__(256) void prep_kernel(
    const float* __restrict__ hs, unsigned short* __restrict__ hsb,
    const float* __restrict__ bq, const float* __restrict__ bk, const float* __restrict__ bv,
    float* __restrict__ cbias, float* __restrict__ cst, float* __restrict__ snt,
    const float* __restrict__ Wq, const float* __restrict__ Wk,
    const float* __restrict__ Wv, const float* __restrict__ Wo,
    unsigned short* __restrict__ wqkvT, unsigned short* __restrict__ woT) {
    __shared__ unsigned short t[32][33];
    const int b = blockIdx.x, tid = threadIdx.x;
    if (b < 4096) {
        int i = b * 256 + tid;
        float4 v = ((const float4*)hs)[i];
        ushort4 o;
        o.x = f2bf(v.x); o.y = f2bf(v.y); o.z = f2bf(v.z); o.w = f2bf(v.w);
        ((ushort4*)hsb)[i] = o;
    } else if (b < 4608) {
        int idx = (b - 4096) * 256 + tid;
        int s = idx >> 6, f = idx & 63;
        float inv = __expf(-(float)f * (logf(10000.f) / 64.f));
        float ang = (float)s * inv;
        float si, co;
        sincosf(ang, &si, &co);
        cst[idx] = co;
        snt[idx] = si;
    } else if (b < 4620) {
        int i = (b - 4608) * 256 + tid;
        if (i < 3072) {
            float v;
            if (i < 2048) v = bq[i];
            else if (i < 2560) v = bk[i - 2048];
            else v = bv[i - 2560];
            cbias[i] = v;
        }
    } else if (b < 8716) {
        tile_transpose(Wq, wqkvT, 2048, 2048, 0, b - 4620, 64, t);
    } else if (b < 9740) {
        tile_transpose(Wk, wqkvT, 512, 2048, 2048, b - 8716, 16, t);
    } else if (b < 10764) {
        tile_transpose(Wv, wqkvT, 512, 2048, 2560, b - 9740, 16, t);
    } else {
        tile_transpose(Wo, woT, 2048, 2048, 0, b - 10764, 64, t);
    }
}

// ---------------- GEMM: C[M,N] = A[M,K] * Bt[N,K]^T (+bias) ----------------
// 128x128 tile, BK=32, triple-buffered LDS, depth-2 global_load_lds prefetch,
// counted vmcnt, both-sides chunk swizzle, setprio. Waves own 32-row slabs
// (acc[2][8]) so the RoPE partner col d^64 is acc[m][n^4] in the SAME lane.
// EPI: 0 = plain f32 C, 1 = fused RoPE + Qr/Kr/Vt layout epilogue.

template <int EPI>
__global__ __launch_bounds__(256) void gemm_pipe(
    const unsigned short* __restrict__ A, const unsigned short* __restrict__ Bt,
    float* __restrict__ C, const float* __restrict__ bias, int M, int N, int K,
    unsigned short* __restrict__ Qr, unsigned short* __restrict__ Kr,
    unsigned short* __restrict__ Vt,
    const float* __restrict__ cst, const float* __restrict__ snt) {
    __shared__ unsigned short Al[3][128 * 32];
    __shared__ unsigned short Bl[3][128 * 32];
    const int tid = threadIdx.x, lane = tid & 63, w = tid >> 6;
    const int lo = lane & 15, hi = lane >> 4;
    const int nbn = N >> 7;
    // bijective XCD swizzle (grid % 8 == 0 for all launches here)
    const int nwg8 = gridDim.x >> 3;
    const int wg = (blockIdx.x & 7) * nwg8 + (blockIdx.x >> 3);
    const int bm = wg / nbn, bn = wg % nbn;
    const int m0 = bm << 7, n0 = bn << 7;
    const size_t Kb = (size_t)K * 2;

    const char* Ab = (const char*)A + (size_t)m0 * Kb;
    const char* Bb = (const char*)Bt + (size_t)n0 * Kb;
    char* Alb = (char*)&Al[0][0];
    char* Blb = (char*)&Bl[0][0];

    // staging: LDS dest linear, global source chunk-swizzled (inverse of read swz)
    const int L0 = tid * 16;
    const int L1 = 4096 + tid * 16;
    const int r0 = L0 >> 6, r1 = L1 >> 6;
    const size_t go0 = (size_t)r0 * Kb + ((((L0 >> 4) & 3) ^ (r0 & 3)) << 4);
    const size_t go1 = (size_t)r1 * Kb + ((((L1 >> 4) & 3) ^ (r1 & 3)) << 4);

    auto stage = [&](int buf, int kt) {
        const char* Ak = Ab + (size_t)kt * 64;
        const char* Bk = Bb + (size_t)kt * 64;
        char* Ad = Alb + buf * 8192;
        char* Bd = Blb + buf * 8192;
        gload16(Ak + go0, Ad + L0);
        gload16(Ak + go1, Ad + L1);
        gload16(Bk + go0, Bd + L0);
        gload16(Bk + go1, Bd + L1);
    };

    f32x4 acc[2][8] = {};
    const int NT = K >> 5;
    const int swz = (hi ^ (lo & 3)) << 4;  // fragment-row&3 == lo&3 everywhere

    stage(0, 0);
    stage(1, 1);
    int buf = 0, nstage = 2;
    for (int kt = 0; kt < NT; ++kt) {
        if (kt < NT - 1)
            asm volatile("s_waitcnt vmcnt(4)" ::: "memory");
        else
            asm volatile("s_waitcnt vmcnt(0)" ::: "memory");
        __builtin_amdgcn_s_barrier();

        const char* Ar = Alb + buf * 8192;
        const char* Br = Blb + buf * 8192;
        short8 af[2], bfr[8];
#pragma unroll
        for (int m = 0; m < 2; m++)
            af[m] = *(const short8*)(Ar + (w * 32 + m * 16 + lo) * 64 + swz);
#pragma unroll
        for (int n = 0; n < 8; n++)
            bfr[n] = *(const short8*)(Br + (n * 16 + lo) * 64 + swz);
        asm volatile("s_waitcnt lgkmcnt(0)" ::: "memory");
        __builtin_amdgcn_s_barrier();

        if (kt + 2 < NT) {
            int bst = nstage;
            bst = (bst >= 3) ? bst - 3 : bst;
            stage(bst, kt + 2);
            nstage = bst + 1;
        }
        __builtin_amdgcn_sched_barrier(0);

        __builtin_amdgcn_s_setprio(1);
#pragma unroll
        for (int m = 0; m < 2; m++)
#pragma unroll
            for (int n = 0; n < 8; n++)
                acc[m][n] = __builtin_amdgcn_mfma_f32_16x16x32_bf16(af[m], bfr[n], acc[m][n], 0, 0, 0);
        __builtin_amdgcn_s_setprio(0);

        buf = (buf == 2) ? 0 : buf + 1;
    }

    const int sbase = m0 + w * 32 + hi * 4;  // + m*16 + r
    if constexpr (EPI == 0) {
#pragma unroll
        for (int m = 0; m < 2; m++) {
            const int row = sbase + m * 16;
#pragma unroll
            for (int n = 0; n < 8; n++) {
                const int col = n0 + n * 16 + lo;
                const float badd = bias ? bias[col] : 0.f;
#pragma unroll
                for (int r = 0; r < 4; r++)
                    C[(size_t)(row + r) * N + col] = acc[m][n][r] + badd;
            }
        }
    } else {
        // bn: 0..15 -> Q head bn; 16..19 -> K head bn-16; 20..23 -> V head bn-20
        if (bn < 20) {
            // preload cos/sin for this lane's (s, f) needs
            float csv[2][4][4], snv[2][4][4];
#pragma unroll
            for (int m = 0; m < 2; m++)
#pragma unroll
                for (int r = 0; r < 4; r++) {
                    const int s = sbase + m * 16 + r;
#pragma unroll
                    for (int fi = 0; fi < 4; fi++) {
                        const int f = fi * 16 + lo;
                        csv[m][r][fi] = cst[s * 64 + f];
                        snv[m][r][fi] = snt[s * 64 + f];
                    }
                }
            unsigned short* dst = (bn < 16) ? (Qr + (size_t)bn * S_LEN * 128)
                                            : (Kr + (size_t)(bn - 16) * S_LEN * 128);
#pragma unroll
            for (int m = 0; m < 2; m++) {
#pragma unroll
                for (int n = 0; n < 8; n++) {
                    const int d = n * 16 + lo;
                    const float badd = bias[n0 + d];
                    const float badd2 = bias[n0 + (d ^ 64)];
#pragma unroll
                    for (int r = 0; r < 4; r++) {
                        const float x = acc[m][n][r] + badd;
                        const float y = acc[m][n ^ 4][r] + badd2;
                        const float cs = csv[m][r][n & 3];
                        const float sn = snv[m][r][n & 3];
                        const float out = (n < 4) ? x * cs - y * sn : x * cs + y * sn;
                        const int s = sbase + m * 16 + r;
                        dst[(size_t)s * 128 + d] = f2bf(out);
                    }
                }
            }
        } else {
            const int kvh = bn - 20;
#pragma unroll
            for (int m = 0; m < 2; m++) {
                const int s0r = sbase + m * 16;
#pragma unroll
                for (int n = 0; n < 8; n++) {
                    const int d = n * 16 + lo;
                    const float badd = bias[n0 + d];
                    ushort4 pk;
                    pk.x = f2bf(acc[m][n][0] + badd);
                    pk.y = f2bf(acc[m][n][1] + badd);
                    pk.z = f2bf(acc[m][n][2] + badd);
                    pk.w = f2bf(acc[m][n][3] + badd);
                    *(ushort4*)(Vt + (size_t)(kvh * 128 + d) * S_LEN + s0r) = pk;
                }
            }
        }
    }
}

// ---------------- flash attention, sliding window, GQA ----------------

__global__ __launch_bounds__(256) void attn_kernel(const unsigned short* __restrict__ Qr,
                                                   const unsigned short* __restrict__ Kr,
                                                   const unsigned short* __restrict__ Vt,
                                                   const float* __restrict__ mg,
                                                   unsigned short* __restrict__ Ao) {
    __shared__ unsigned short Kl[2][64 * 128];  // swizzled rows of 256B
    __shared__ unsigned short Vl[2][128 * 64];  // swizzled rows of 128B
    __shared__ unsigned short Pl[4][16 * 64];   // per-wave, swizzled rows of 128B
    const int tid = threadIdx.x, lane = tid & 63, w = tid >> 6;
    const int h = blockIdx.y, qt = blockIdx.x;
    const int kvh = h >> 2;
    const int q0 = qt * 64;
    const int lo = lane & 15, hi = lane >> 4;

    const unsigned short* Qb =
        Qr + ((size_t)h * S_LEN + q0 + w * 16 + lo) * 128 + hi * 8;
    short8 qf[4];
#pragma unroll
    for (int ks = 0; ks < 4; ++ks) qf[ks] = *(const short8*)(Qb + ks * 32);

    const float gate = 1.f / (1.f + __expf(-mg[h]));
    const float fac = 1.f - gate;

    const short8 ones = {16256, 16256, 16256, 16256, 16256, 16256, 16256, 16256};  // bf16 1.0

    float mrow[4] = {-INFINITY, -INFINITY, -INFINITY, -INFINITY};
    f32x4 o[8] = {};
    f32x4 ol = {};  // row-sum accumulator (l) via ones-MFMA

    const char* Kg = (const char*)(Kr + (size_t)kvh * S_LEN * 128);
    const char* Vg = (const char*)(Vt + (size_t)kvh * 128 * S_LEN);
    char* Klb = (char*)&Kl[0][0];
    char* Vlb = (char*)&Vl[0][0];
    const int wb = w * 1024;

    auto stage = [&](int buf, int kt) {
        const int k0 = kt * 64;
#pragma unroll
        for (int iss = 0; iss < 4; ++iss) {
            int lin = iss * 4096 + tid * 16;
            int row = lin >> 8;
            int chunk = (lin >> 4) & 15;
            gload16(Kg + (size_t)(k0 + row) * 256 + ((chunk ^ (row & 7)) << 4),
                    Klb + buf * 16384 + iss * 4096 + wb);
            int d = lin >> 7;
            int vchunk = (lin >> 4) & 7;
            gload16(Vg + (size_t)d * (S_LEN * 2) + (size_t)k0 * 2 + ((vchunk ^ (d & 7)) << 4),
                    Vlb + buf * 16384 + iss * 4096 + wb);
        }
    };

    const int qmin = q0 + w * 16;
    const int t0 = (q0 >= 1023) ? (q0 - 1023) >> 6 : 0;
    stage(0, t0);
    for (int kt = t0; kt <= qt; ++kt) {
        __syncthreads();
        if (kt < qt) stage((kt - t0 + 1) & 1, kt + 1);
        const int buf = (kt - t0) & 1;
        const int k0 = kt * 64;
        const char* Kb = Klb + buf * 16384;
        const char* Vb = Vlb + buf * 16384;

        // QK^T
        f32x4 sc[4];
        __builtin_amdgcn_s_setprio(1);
#pragma unroll
        for (int t = 0; t < 4; t++) {
            sc[t] = (f32x4){0.f, 0.f, 0.f, 0.f};
            const int krow = t * 16 + lo;
#pragma unroll
            for (int ks = 0; ks < 4; ks++) {
                const int chunk = ks * 4 + hi;
                short8 kf = *(const short8*)(Kb + krow * 256 + ((chunk ^ (krow & 7)) << 4));
                sc[t] = __builtin_amdgcn_mfma_f32_16x16x32_bf16(qf[ks], kf, sc[t], 0, 0, 0);
            }
        }
        __builtin_amdgcn_s_setprio(0);

        // scores + mask (wave-uniform interior fast path)
        const bool full = (k0 + 63 <= qmin) && (k0 >= qmin + 15 - (WINDOW - 1));
        float ps[4][4];
        float mt[4];
        if (full) {
#pragma unroll
            for (int r = 0; r < 4; r++) {
                float m0v = -INFINITY;
#pragma unroll
                for (int t = 0; t < 4; t++) {
                    float sv = sc[t][r] * SCALE;
                    ps[t][r] = sv;
                    m0v = fmaxf(m0v, sv);
                }
                mt[r] = m0v;
            }
        } else {
#pragma unroll
            for (int r = 0; r < 4; r++) {
                const int q = qmin + hi * 4 + r;
                float m0v = -INFINITY;
#pragma unroll
                for (int t = 0; t < 4; t++) {
                    const int k = k0 + t * 16 + lo;
                    const bool valid = (k <= q) && (q - k < WINDOW);
                    float sv = valid ? sc[t][r] * SCALE : -INFINITY;
                    ps[t][r] = sv;
                    m0v = fmaxf(m0v, sv);
                }
                mt[r] = m0v;
            }
        }

        // online max with defer (THR=8); l handled by ones-MFMA below
        float alpha[4];
        bool need = false;
#pragma unroll
        for (int r = 0; r < 4; r++) {
#pragma unroll
            for (int off = 1; off < 16; off <<= 1) mt[r] = fmaxf(mt[r], __shfl_xor(mt[r], off, 64));
            const float mo = mrow[r];
            const float mn = (mt[r] > mo + 8.f) ? mt[r] : mo;
            const bool resc = (mn != mo);
            alpha[r] = resc ? __expf(mo - mn) : 1.f;
            need = need || resc;
            mrow[r] = mn;
            const float mn_e = (mn == -INFINITY) ? 0.f : mn;
#pragma unroll
            for (int t = 0; t < 4; t++) ps[t][r] = __expf(ps[t][r] - mn_e);
        }

        // P -> LDS (bf16, swizzled 128B rows)
        char* Pw = (char*)&Pl[w][0];
#pragma unroll
        for (int r = 0; r < 4; r++) {
            const int prow = hi * 4 + r;
#pragma unroll
            for (int t = 0; t < 4; t++) {
                const int col = t * 16 + lo;
                const int chunk = col >> 3;
                *(unsigned short*)(Pw + prow * 128 + ((chunk ^ (prow & 7)) << 4) + (col & 7) * 2) =
                    f2bf(ps[t][r]);
            }
        }
        asm volatile("s_waitcnt lgkmcnt(0)" ::: "memory");
        __builtin_amdgcn_sched_barrier(0);

        // rescale O and l (skipped when all rows deferred)
        if (__any(need)) {
#pragma unroll
            for (int n = 0; n < 8; n++)
#pragma unroll
                for (int r = 0; r < 4; r++) o[n][r] *= alpha[r];
#pragma unroll
            for (int r = 0; r < 4; r++) ol[r] *= alpha[r];
        }

        // hoisted P fragments
        short8 pa[2];
#pragma unroll
        for (int ks = 0; ks < 2; ++ks) {
            const int chunk = ks * 4 + hi;
            pa[ks] = *(const short8*)(Pw + lo * 128 + ((chunk ^ (lo & 7)) << 4));
        }

        // PV + l accumulation
        __builtin_amdgcn_s_setprio(1);
        ol = __builtin_amdgcn_mfma_f32_16x16x32_bf16(pa[0], ones, ol, 0, 0, 0);
        ol = __builtin_amdgcn_mfma_f32_16x16x32_bf16(pa[1], ones, ol, 0, 0, 0);
#pragma unroll
        for (int n = 0; n < 8; n++) {
            const int d = n * 16 + lo;
#pragma unroll
            for (int ks = 0; ks < 2; ++ks) {
                const int chunk = ks * 4 + hi;
                short8 vbf = *(const short8*)(Vb + d * 128 + ((chunk ^ (d & 7)) << 4));
                o[n] = __builtin_amdgcn_mfma_f32_16x16x32_bf16(pa[ks], vbf, o[n], 0, 0, 0);
            }
        }
        __builtin_amdgcn_s_setprio(0);
        __syncthreads();
    }

    // epilogue: out = (1-gate) * local / l
#pragma unroll
    for (int r = 0; r < 4; r++) {
        const int s = q0 + w * 16 + hi * 4 + r;
        const float inv = fac / ol[r];
#pragma unroll
        for (int n = 0; n < 8; n++) {
            const int d = n * 16 + lo;
            Ao[(size_t)s * 2048 + h * 128 + d] = f2bf(o[n][r] * inv);
        }
    }
}

// ---------------- launch ----------------

extern "C" void kernel_launch(void* const* d_in, const int* in_sizes, int n_in,
                              void* d_out, int out_size, void* d_ws, size_t ws_size,
                              hipStream_t stream) {
    const float* hs = (const float*)d_in[0];
    const float* Wq = (const float*)d_in[1];
    const float* bq = (const float*)d_in[2];
    const float* Wk = (const float*)d_in[3];
    const float* bk = (const float*)d_in[4];
    const float* Wv = (const float*)d_in[5];
    const float* bv = (const float*)d_in[6];
    const float* Wo = (const float*)d_in[7];
    const float* mg = (const float*)d_in[8];

    char* ws = (char*)d_ws;
    unsigned short* hsb   = (unsigned short*)(ws + 0);          // 8 MB, dead after gemm1
    unsigned short* attnb = (unsigned short*)(ws + 0);          // reuses hsb region
    unsigned short* wqkvT = (unsigned short*)(ws + 8388608);    // 12 MB
    unsigned short* woT   = (unsigned short*)(ws + 20971520);   // 8 MB
    unsigned short* Qrb   = (unsigned short*)(ws + 29360128);   // 8 MB
    unsigned short* Krb   = (unsigned short*)(ws + 37748736);   // 2 MB
    unsigned short* Vtb   = (unsigned short*)(ws + 39845888);   // 2 MB
    float*          cbias = (float*)(ws + 41943040);            // 12 KB
    float*          cst   = (float*)(ws + 41959424);            // 512 KB
    float*          snt   = (float*)(ws + 42483712);            // 512 KB

    // 1. fused prep
    prep_kernel<<<14860, 256, 0, stream>>>(hs, hsb, bq, bk, bv, cbias, cst, snt,
                                           Wq, Wk, Wv, Wo, wqkvT, woT);

    // 2. QKV projection + fused bias/RoPE/layout epilogue
    gemm_pipe<1><<<16 * 24, 256, 0, stream>>>(hsb, wqkvT, nullptr, cbias, 2048, 3072, 2048,
                                              Qrb, Krb, Vtb, cst, snt);

    // 3. attention (attnb overwrites hsb region; hsb dead)
    attn_kernel<<<dim3(32, 16), 256, 0, stream>>>(Qrb, Krb, Vtb, mg, attnb);

    // 4. output projection -> d_out (f32)
    gemm_pipe<0><<<16 * 16, 256, 0, stream>>>(attnb, woT, (float*)d_out, nullptr, 2048, 2048, 2048,
                                              nullptr, nullptr, nullptr, nullptr, nullptr);
}